// Round 4
// baseline (34.171 us; speedup 1.0000x reference)
//
#include <hip/hip_runtime.h>
#include <math.h>

#define HH 256
#define WW 256
#define NPTS 1024
#define RANK 6
#define NC 128
#define PIX (HH * WW)
#define SIGMA_CUT 18.0f
#define PSTRIDE 20  // floats per packed gaussian (17 used, padded to 5xfloat4)

typedef float vf4 __attribute__((ext_vector_type(4)));

__device__ __forceinline__ float softplus_f(float x) {
    return fmaxf(x, 0.0f) + log1pf(expf(-fabsf(x)));
}

// ---------------------------------------------------------------------------
// Kernel 1: prep. Blocks 0..3: pack per-gaussian params + bbox into ws.
// Block 4: E = clip(endmember + 0.1*tanh(s)*tanh(U@V), 1e-6) -> d_out.
// ---------------------------------------------------------------------------
__global__ __launch_bounds__(256) void prep_kernel(
    const float* __restrict__ xyz, const float* __restrict__ cholesky,
    const float* __restrict__ features_dc,
    const float* __restrict__ gabor_freqs,
    const float* __restrict__ gabor_weights,
    const float* __restrict__ opacity,
    const float* __restrict__ lora_U, const float* __restrict__ lora_V,
    const float* __restrict__ lora_scale_logit,
    const float* __restrict__ endmember,
    float* __restrict__ params, float* __restrict__ bbox,
    float* __restrict__ Eout)
{
    const int b = blockIdx.x;
    const int t = threadIdx.x;
    if (b < 4) {
        const int n = b * 256 + t;
        float mx = tanhf(xyz[n * 2 + 0]);
        float my = tanhf(xyz[n * 2 + 1]);
        float cx = (mx * 0.5f + 0.5f) * (float)WW;
        float cy = (my * 0.5f + 0.5f) * (float)HH;

        float l1 = cholesky[n * 3 + 0] + 0.5f;
        float l2 = cholesky[n * 3 + 1];
        float l3 = cholesky[n * 3 + 2] + 0.5f;
        float a = l1 * l1;
        float bb = l1 * l2;
        float c = l2 * l2 + l3 * l3;
        float inv = 1.0f / (a * c - bb * bb);

        float pk[PSTRIDE];
        pk[0] = cx;
        pk[1] = cy;
        pk[2] = c * inv;    // ca
        pk[3] = -bb * inv;  // cb
        pk[4] = a * inv;    // cc
        pk[5] = expf(gabor_freqs[(n * 2 + 0) * 2 + 0]);  // fx0
        pk[6] = expf(gabor_freqs[(n * 2 + 0) * 2 + 1]);  // fy0
        pk[7] = expf(gabor_freqs[(n * 2 + 1) * 2 + 0]);  // fx1
        pk[8] = expf(gabor_freqs[(n * 2 + 1) * 2 + 1]);  // fy1
        pk[9] = 1.0f / (1.0f + expf(-gabor_weights[n * 2 + 0]));  // gw0
        pk[10] = 1.0f / (1.0f + expf(-gabor_weights[n * 2 + 1])); // gw1
        float op = opacity[n];
#pragma unroll
        for (int r = 0; r < RANK; ++r)
            pk[11 + r] = softplus_f(features_dc[n * RANK + r]) * op;
        pk[17] = 0.0f; pk[18] = 0.0f; pk[19] = 0.0f;

        vf4* dst = (vf4*)(params + (size_t)n * PSTRIDE);
#pragma unroll
        for (int k = 0; k < 5; ++k) {
            vf4 v = { pk[k * 4 + 0], pk[k * 4 + 1], pk[k * 4 + 2], pk[k * 4 + 3] };
            dst[k] = v;
        }

        float rx = sqrtf(fmaxf(2.0f * SIGMA_CUT * a, 0.0f));
        float ry = sqrtf(fmaxf(2.0f * SIGMA_CUT * c, 0.0f));
        vf4 bv = { cx, cy, rx, ry };
        ((vf4*)bbox)[n] = bv;
    } else {
        float scale = 0.1f * tanhf(lora_scale_logit[0]);
#pragma unroll
        for (int k = 0; k < 3; ++k) {
            int i = k * 256 + t;  // i < 768
            int r = i >> 7;
            int c = i & 127;
            float dot = lora_U[r * 2 + 0] * lora_V[c] +
                        lora_U[r * 2 + 1] * lora_V[NC + c];
            Eout[i] = fmaxf(endmember[i] + scale * tanhf(dot), 1e-6f);
        }
    }
}

// ---------------------------------------------------------------------------
// Kernel 2: fused gather splat + render. One block per 64x4 pixel tile;
// thread owns 1 pixel, acc[6] in registers (no atomics, no zero pass).
// Gaussians culled per tile in 4 chunks of 256 via ballot compaction
// (deterministic order), evaluated from an LDS list, then per-pixel 6x128
// matmul with E staged in LDS; nontemporal stores.
// ---------------------------------------------------------------------------
__global__ __launch_bounds__(256) void tile_kernel(
    const float* __restrict__ params, const float* __restrict__ bbox,
    const float* __restrict__ E,
    float* __restrict__ render, float* __restrict__ abund_out)
{
    __shared__ float Els[NC * 8];             // E as [c][8] (r padded to 8)
    __shared__ float glist[256 * PSTRIDE];    // 20 KB compacted gaussians
    __shared__ int wcnt[4];

    const int t = threadIdx.x;
    const int b = blockIdx.x;
    const int tx = (b & 3) * 64;
    const int ty = (b >> 2) * 4;
    const int x = tx + (t & 63);
    const int y = ty + (t >> 6);
    const float px = (float)x + 0.5f;
    const float py = (float)y + 0.5f;

    // stage E transposed+padded
    for (int i = t; i < NC * RANK; i += 256) {
        int r = i >> 7;       // E[r][c], r<6
        int c = i & 127;
        Els[c * 8 + r] = E[i];
    }
    if (t < NC) { Els[t * 8 + 6] = 0.0f; Els[t * 8 + 7] = 0.0f; }

    float acc[RANK] = {0.f, 0.f, 0.f, 0.f, 0.f, 0.f};

    const float txmin = (float)tx, txmax = (float)(tx + 64);
    const float tymin = (float)ty, tymax = (float)(ty + 4);
    const int wv = t >> 6;
    const int ln = t & 63;

    for (int chunk = 0; chunk < 4; ++chunk) {
        const int gid = chunk * 256 + t;
        vf4 bb = ((const vf4*)bbox)[gid];
        bool hit = (bb.x - bb.z <= txmax) && (bb.x + bb.z >= txmin) &&
                   (bb.y - bb.w <= tymax) && (bb.y + bb.w >= tymin);
        unsigned long long m = __ballot(hit);

        __syncthreads();  // previous chunk's eval done before overwriting
        if (ln == 0) wcnt[wv] = __popcll(m);
        __syncthreads();

        int base = 0;
#pragma unroll
        for (int w = 0; w < 4; ++w) if (w < wv) base += wcnt[w];
        const int total = wcnt[0] + wcnt[1] + wcnt[2] + wcnt[3];

        if (hit) {
            int pos = base + __popcll(m & ((1ull << ln) - 1ull));
            const vf4* src = (const vf4*)(params + (size_t)gid * PSTRIDE);
            vf4* dst = (vf4*)(glist + pos * PSTRIDE);
#pragma unroll
            for (int k = 0; k < 5; ++k) dst[k] = src[k];
        }
        __syncthreads();

        for (int i = 0; i < total; ++i) {
            const float* g = glist + i * PSTRIDE;
            float dx = px - g[0];
            float dy = py - g[1];
            float sigma = 0.5f * (g[2] * dx * dx + g[4] * dy * dy) + g[3] * dx * dy;
            if (sigma < 0.0f || sigma > SIGMA_CUT) continue;
            float mod = 1.0f + g[9] * cosf(g[5] * dx + g[6] * dy)
                             + g[10] * cosf(g[7] * dx + g[8] * dy);
            float wm = expf(-sigma) * mod;
#pragma unroll
            for (int r = 0; r < RANK; ++r)
                acc[r] = fmaf(wm, g[11 + r], acc[r]);
        }
    }

#pragma unroll
    for (int r = 0; r < RANK; ++r) acc[r] = fmaxf(acc[r], 0.0f);

    // abundance output (pixel-major [p][r])
    const int p = y * WW + x;
    float* ao = abund_out + (size_t)p * RANK;
#pragma unroll
    for (int r = 0; r < RANK; ++r)
        __builtin_nontemporal_store(acc[r], ao + r);

    // render: out[c][p] = dot6(acc, E[:,c]); wave = contiguous 64-px row
    float* rp = render + p;
#pragma unroll 4
    for (int c = 0; c < NC; ++c) {
        const vf4 e0 = *(const vf4*)(Els + c * 8);
        const vf4 e1 = *(const vf4*)(Els + c * 8 + 4);
        float o = acc[0] * e0.x;
        o = fmaf(acc[1], e0.y, o);
        o = fmaf(acc[2], e0.z, o);
        o = fmaf(acc[3], e0.w, o);
        o = fmaf(acc[4], e1.x, o);
        o = fmaf(acc[5], e1.y, o);
        __builtin_nontemporal_store(o, rp + (size_t)c * PIX);
    }
}

extern "C" void kernel_launch(void* const* d_in, const int* in_sizes, int n_in,
                              void* d_out, int out_size, void* d_ws, size_t ws_size,
                              hipStream_t stream)
{
    const float* xyz             = (const float*)d_in[0];
    const float* cholesky        = (const float*)d_in[1];
    const float* features_dc     = (const float*)d_in[2];
    const float* gabor_freqs     = (const float*)d_in[3];
    const float* gabor_weights   = (const float*)d_in[4];
    const float* lora_U          = (const float*)d_in[5];
    const float* lora_V          = (const float*)d_in[6];
    const float* lora_scale_logit= (const float*)d_in[7];
    const float* opacity         = (const float*)d_in[8];
    const float* endmember       = (const float*)d_in[9];

    float* out    = (float*)d_out;
    float* render = out;                               // NC*PIX
    float* abund  = out + (size_t)NC * PIX;            // PIX*RANK
    float* Eout   = abund + (size_t)PIX * RANK;        // RANK*NC

    float* params = (float*)d_ws;                      // 1024*20*4 = 80 KB
    float* bbox   = params + (size_t)NPTS * PSTRIDE;   // 1024*4*4  = 16 KB

    prep_kernel<<<5, 256, 0, stream>>>(
        xyz, cholesky, features_dc, gabor_freqs, gabor_weights, opacity,
        lora_U, lora_V, lora_scale_logit, endmember, params, bbox, Eout);

    tile_kernel<<<256, 256, 0, stream>>>(params, bbox, Eout, render, abund);
}

// Round 5
// 22.609 us; speedup vs baseline: 1.5114x; 1.5114x over previous
//
#include <hip/hip_runtime.h>
#include <math.h>

#define HH 256
#define WW 256
#define NPTS 1024
#define RANK 6
#define NC 128
#define PIX (HH * WW)
#define SIGMA_CUT 18.0f
#define PSTRIDE 20   // floats per packed gaussian (17 used, pad to 5*vf4)
#define MAXG 256     // per-tile gaussian list capacity (worst tile ~40 expected)

typedef float vf4 __attribute__((ext_vector_type(4)));

__device__ __forceinline__ float softplus_f(float x) {
    return fmaxf(x, 0.0f) + log1pf(__expf(-fabsf(x)));
}

// ---------------------------------------------------------------------------
// Single fused kernel. 512 blocks = 256 tiles (64x4 px) x 2 channel-groups.
// Each block independently: (1) E-slice into LDS, (2) cheap bbox cull of all
// 1024 gaussians (ballot-compact indices), (3) full params for survivors,
// (4) per-pixel register accumulation (1 px/thread), (5) clamp + NT stores.
// No inter-block deps -> one dispatch, no atomics, no abund round-trip.
// ---------------------------------------------------------------------------
__global__ __launch_bounds__(256) void fused_kernel(
    const float* __restrict__ xyz, const float* __restrict__ chol,
    const float* __restrict__ fdc, const float* __restrict__ gfreq,
    const float* __restrict__ gwt, const float* __restrict__ opac,
    const float* __restrict__ lU, const float* __restrict__ lV,
    const float* __restrict__ lS, const float* __restrict__ em,
    float* __restrict__ render, float* __restrict__ abund,
    float* __restrict__ Eout)
{
    __shared__ float Els[64 * 8];              // E[ch_local][r], r padded to 8
    __shared__ float glist[MAXG * PSTRIDE];    // 20 KB packed survivors
    __shared__ int   idxl[MAXG];
    __shared__ int   wcnt[4];

    const int t    = threadIdx.x;
    const int bid  = blockIdx.x;
    const int cg   = bid & 1;          // channel group: c in [cg*64, cg*64+64)
    const int tile = bid >> 1;         // 256 tiles of 64x4
    const int tx   = (tile & 3) * 64;
    const int ty   = (tile >> 2) * 4;
    const int x    = tx + (t & 63);
    const int y    = ty + (t >> 6);
    const int p    = y * WW + x;
    const float px = (float)x + 0.5f;
    const float py = (float)y + 0.5f;
    const int wv   = t >> 6;
    const int ln   = t & 63;

    // ---- E slice (and block 0 writes the full E output) ----
    {
        float scale = 0.1f * tanhf(lS[0]);
        for (int i = t; i < 64 * RANK; i += 256) {
            int r = i >> 6; int cl = i & 63; int c = cg * 64 + cl;
            float dot = lU[r * 2] * lV[c] + lU[r * 2 + 1] * lV[NC + c];
            Els[cl * 8 + r] = fmaxf(em[r * NC + c] + scale * tanhf(dot), 1e-6f);
        }
        if (t < 64) { Els[t * 8 + 6] = 0.0f; Els[t * 8 + 7] = 0.0f; }
        if (bid == 0) {
            for (int i = t; i < RANK * NC; i += 256) {
                int r = i >> 7; int c = i & 127;
                float dot = lU[r * 2] * lV[c] + lU[r * 2 + 1] * lV[NC + c];
                Eout[i] = fmaxf(em[i] + scale * tanhf(dot), 1e-6f);
            }
        }
    }

    // ---- cheap cull: bbox (|dx|<=6*sqrt(a), |dy|<=6*sqrt(c)) vs tile ----
    const float txmin = (float)tx, txmax = (float)(tx + 64);
    const float tymin = (float)ty, tymax = (float)(ty + 4);
    int total = 0;
    for (int k = 0; k < 4; ++k) {
        const int gid = k * 256 + t;
        float cx = (tanhf(xyz[gid * 2 + 0]) * 0.5f + 0.5f) * (float)WW;
        float cy = (tanhf(xyz[gid * 2 + 1]) * 0.5f + 0.5f) * (float)HH;
        float l1 = chol[gid * 3 + 0] + 0.5f;
        float l2 = chol[gid * 3 + 1];
        float l3 = chol[gid * 3 + 2] + 0.5f;
        float a = l1 * l1;
        float c = l2 * l2 + l3 * l3;
        float rx = 6.0f * sqrtf(a);   // sqrt(2*SIGMA_CUT*a), SIGMA_CUT=18
        float ry = 6.0f * sqrtf(c);
        bool hit = (cx - rx <= txmax) && (cx + rx >= txmin) &&
                   (cy - ry <= tymax) && (cy + ry >= tymin);
        unsigned long long m = __ballot(hit);
        if (ln == 0) wcnt[wv] = __popcll(m);
        __syncthreads();
        int base = total;
        for (int w = 0; w < 4; ++w) { if (w < wv) base += wcnt[w]; }
        total += wcnt[0] + wcnt[1] + wcnt[2] + wcnt[3];
        if (hit) {
            int pos = base + __popcll(m & ((1ull << ln) - 1ull));
            if (pos < MAXG) idxl[pos] = gid;
        }
        __syncthreads();   // also guards wcnt reuse next chunk
    }
    const int T = min(total, MAXG);

    // ---- full params for survivors (deterministic order = gid ascending) ----
    for (int j = t; j < T; j += 256) {
        const int n = idxl[j];
        float cx = (tanhf(xyz[n * 2 + 0]) * 0.5f + 0.5f) * (float)WW;
        float cy = (tanhf(xyz[n * 2 + 1]) * 0.5f + 0.5f) * (float)HH;
        float l1 = chol[n * 3 + 0] + 0.5f;
        float l2 = chol[n * 3 + 1];
        float l3 = chol[n * 3 + 2] + 0.5f;
        float a = l1 * l1, bb = l1 * l2, c = l2 * l2 + l3 * l3;
        float inv = 1.0f / (a * c - bb * bb);
        float* g = glist + j * PSTRIDE;
        g[0] = cx; g[1] = cy;
        g[2] = c * inv; g[3] = -bb * inv; g[4] = a * inv;
        g[5] = __expf(gfreq[n * 4 + 0]);   // fx0
        g[6] = __expf(gfreq[n * 4 + 1]);   // fy0
        g[7] = __expf(gfreq[n * 4 + 2]);   // fx1
        g[8] = __expf(gfreq[n * 4 + 3]);   // fy1
        g[9]  = 1.0f / (1.0f + __expf(-gwt[n * 2 + 0]));
        g[10] = 1.0f / (1.0f + __expf(-gwt[n * 2 + 1]));
        float op = opac[n];
#pragma unroll
        for (int r = 0; r < RANK; ++r)
            g[11 + r] = softplus_f(fdc[n * RANK + r]) * op;
    }
    __syncthreads();

    // ---- per-pixel accumulation in registers ----
    float acc[RANK] = {0.f, 0.f, 0.f, 0.f, 0.f, 0.f};
    for (int i = 0; i < T; ++i) {
        const float* g = glist + i * PSTRIDE;   // uniform addr -> LDS broadcast
        float dx = px - g[0];
        float dy = py - g[1];
        float sigma = 0.5f * (g[2] * dx * dx + g[4] * dy * dy) + g[3] * dx * dy;
        if (sigma < 0.0f || sigma > SIGMA_CUT) continue;
        float wm = __expf(-sigma) *
                   (1.0f + g[9]  * __cosf(g[5] * dx + g[6] * dy)
                         + g[10] * __cosf(g[7] * dx + g[8] * dy));
#pragma unroll
        for (int r = 0; r < RANK; ++r)
            acc[r] = fmaf(wm, g[11 + r], acc[r]);
    }
#pragma unroll
    for (int r = 0; r < RANK; ++r) acc[r] = fmaxf(acc[r], 0.0f);

    // ---- abundance output (ch-group 0 only) ----
    if (cg == 0) {
        float* ao = abund + (size_t)p * RANK;
#pragma unroll
        for (int r = 0; r < RANK; ++r)
            __builtin_nontemporal_store(acc[r], ao + r);
    }

    // ---- render: 64 channels, wave = contiguous 256B row per store ----
    float* rp = render + (size_t)cg * 64 * PIX + p;
#pragma unroll 8
    for (int cl = 0; cl < 64; ++cl) {
        const vf4 e0 = *(const vf4*)(Els + cl * 8);
        const vf4 e1 = *(const vf4*)(Els + cl * 8 + 4);
        float o = acc[0] * e0.x;
        o = fmaf(acc[1], e0.y, o);
        o = fmaf(acc[2], e0.z, o);
        o = fmaf(acc[3], e0.w, o);
        o = fmaf(acc[4], e1.x, o);
        o = fmaf(acc[5], e1.y, o);
        __builtin_nontemporal_store(o, rp + (size_t)cl * PIX);
    }
}

extern "C" void kernel_launch(void* const* d_in, const int* in_sizes, int n_in,
                              void* d_out, int out_size, void* d_ws, size_t ws_size,
                              hipStream_t stream)
{
    const float* xyz             = (const float*)d_in[0];
    const float* cholesky        = (const float*)d_in[1];
    const float* features_dc     = (const float*)d_in[2];
    const float* gabor_freqs     = (const float*)d_in[3];
    const float* gabor_weights   = (const float*)d_in[4];
    const float* lora_U          = (const float*)d_in[5];
    const float* lora_V          = (const float*)d_in[6];
    const float* lora_scale_logit= (const float*)d_in[7];
    const float* opacity         = (const float*)d_in[8];
    const float* endmember       = (const float*)d_in[9];

    float* out    = (float*)d_out;
    float* render = out;                               // NC*PIX
    float* abund  = out + (size_t)NC * PIX;            // PIX*RANK
    float* Eout   = abund + (size_t)PIX * RANK;        // RANK*NC

    fused_kernel<<<512, 256, 0, stream>>>(
        xyz, cholesky, features_dc, gabor_freqs, gabor_weights, opacity,
        lora_U, lora_V, lora_scale_logit, endmember, render, abund, Eout);
}

// Round 6
// 20.541 us; speedup vs baseline: 1.6636x; 1.1007x over previous
//
#include <hip/hip_runtime.h>
#include <math.h>

#define HH 256
#define WW 256
#define NPTS 1024
#define RANK 6
#define NC 128
#define PIX (HH * WW)
#define SIGMA_CUT 18.0f
#define PSTRIDE 20   // floats per packed gaussian (17 used, pad to 5*vf4)
#define MAXG 256     // per-tile gaussian list capacity (worst tile ~45 expected)
#define TPAD 264     // transpose row stride (256 + 8): stride-9-like bank spread

typedef float vf4 __attribute__((ext_vector_type(4)));

__device__ __forceinline__ float softplus_f(float x) {
    return fmaxf(x, 0.0f) + log1pf(__expf(-fabsf(x)));
}

// ---------------------------------------------------------------------------
// Single fused kernel. 512 blocks = 256 tiles (64x4 px) x 2 channel-groups.
// Per block: E-slice -> LDS; bbox-cull 1024 gaussians (ballot compaction);
// full params for survivors (packed as 5x vf4 in LDS); per-pixel register
// accumulation (1 px/thread); LDS transpose so each thread outputs
// 4 px x 16 ch with dwordx4 NT stores (1KB/wave-instr).
// ---------------------------------------------------------------------------
__global__ __launch_bounds__(256) void fused_kernel(
    const float* __restrict__ xyz, const float* __restrict__ chol,
    const float* __restrict__ fdc, const float* __restrict__ gfreq,
    const float* __restrict__ gwt, const float* __restrict__ opac,
    const float* __restrict__ lU, const float* __restrict__ lV,
    const float* __restrict__ lS, const float* __restrict__ em,
    float* __restrict__ render, float* __restrict__ abund,
    float* __restrict__ Eout)
{
    __shared__ float Els[64 * 8];              // E[ch_local][r] (8-padded rows)
    __shared__ float glist[MAXG * PSTRIDE];    // 20 KB packed survivors
    __shared__ int   idxl[MAXG];
    __shared__ int   wcnt[4];
    __shared__ float accT[RANK * TPAD];        // transpose buffer, r-major

    const int t    = threadIdx.x;
    const int bid  = blockIdx.x;
    const int cg   = bid & 1;          // channel group: c in [cg*64, cg*64+64)
    const int tile = bid >> 1;         // 256 tiles of 64x4
    const int tx   = (tile & 3) * 64;
    const int ty   = (tile >> 2) * 4;
    const int x    = tx + (t & 63);
    const int y    = ty + (t >> 6);
    const float px = (float)x + 0.5f;
    const float py = (float)y + 0.5f;
    const int wv   = t >> 6;
    const int ln   = t & 63;

    // ---- E slice (block 0 also writes the full E output) ----
    {
        float scale = 0.1f * tanhf(lS[0]);
        for (int i = t; i < 64 * RANK; i += 256) {
            int r = i >> 6; int cl = i & 63; int c = cg * 64 + cl;
            float dot = lU[r * 2] * lV[c] + lU[r * 2 + 1] * lV[NC + c];
            Els[cl * 8 + r] = fmaxf(em[r * NC + c] + scale * tanhf(dot), 1e-6f);
        }
        if (bid == 0) {
            for (int i = t; i < RANK * NC; i += 256) {
                int r = i >> 7; int c = i & 127;
                float dot = lU[r * 2] * lV[c] + lU[r * 2 + 1] * lV[NC + c];
                Eout[i] = fmaxf(em[i] + scale * tanhf(dot), 1e-6f);
            }
        }
    }

    // ---- cheap cull: bbox (|dx|<=6*sqrt(a), |dy|<=6*sqrt(c)) vs tile ----
    const float txmin = (float)tx, txmax = (float)(tx + 64);
    const float tymin = (float)ty, tymax = (float)(ty + 4);
    int total = 0;
    for (int k = 0; k < 4; ++k) {
        const int gid = k * 256 + t;
        float cx = (tanhf(xyz[gid * 2 + 0]) * 0.5f + 0.5f) * (float)WW;
        float cy = (tanhf(xyz[gid * 2 + 1]) * 0.5f + 0.5f) * (float)HH;
        float l1 = chol[gid * 3 + 0] + 0.5f;
        float l2 = chol[gid * 3 + 1];
        float l3 = chol[gid * 3 + 2] + 0.5f;
        float a = l1 * l1;
        float c = l2 * l2 + l3 * l3;
        float rx = 6.0f * sqrtf(a);   // sqrt(2*SIGMA_CUT*a), SIGMA_CUT=18
        float ry = 6.0f * sqrtf(c);
        bool hit = (cx - rx <= txmax) && (cx + rx >= txmin) &&
                   (cy - ry <= tymax) && (cy + ry >= tymin);
        unsigned long long m = __ballot(hit);
        if (ln == 0) wcnt[wv] = __popcll(m);
        __syncthreads();
        int base = total;
        for (int w = 0; w < 4; ++w) { if (w < wv) base += wcnt[w]; }
        total += wcnt[0] + wcnt[1] + wcnt[2] + wcnt[3];
        if (hit) {
            int pos = base + __popcll(m & ((1ull << ln) - 1ull));
            if (pos < MAXG) idxl[pos] = gid;
        }
        __syncthreads();   // guards wcnt reuse next chunk
    }
    const int T = min(total, MAXG);

    // ---- full params for survivors (deterministic order = gid ascending) ----
    // packing: g0={cx,cy,ca,cb} g1={cc,fx0,fy0,fx1} g2={fy1,gw0,gw1,f0}
    //          g3={f1,f2,f3,f4} g4={f5,0,0,0}
    for (int j = t; j < T; j += 256) {
        const int n = idxl[j];
        float cx = (tanhf(xyz[n * 2 + 0]) * 0.5f + 0.5f) * (float)WW;
        float cy = (tanhf(xyz[n * 2 + 1]) * 0.5f + 0.5f) * (float)HH;
        float l1 = chol[n * 3 + 0] + 0.5f;
        float l2 = chol[n * 3 + 1];
        float l3 = chol[n * 3 + 2] + 0.5f;
        float a = l1 * l1, bb = l1 * l2, c = l2 * l2 + l3 * l3;
        float inv = 1.0f / (a * c - bb * bb);
        float* g = glist + j * PSTRIDE;
        g[0] = cx; g[1] = cy;
        g[2] = c * inv; g[3] = -bb * inv; g[4] = a * inv;
        g[5] = __expf(gfreq[n * 4 + 0]);
        g[6] = __expf(gfreq[n * 4 + 1]);
        g[7] = __expf(gfreq[n * 4 + 2]);
        g[8] = __expf(gfreq[n * 4 + 3]);
        g[9]  = 1.0f / (1.0f + __expf(-gwt[n * 2 + 0]));
        g[10] = 1.0f / (1.0f + __expf(-gwt[n * 2 + 1]));
        float op = opac[n];
#pragma unroll
        for (int r = 0; r < RANK; ++r)
            g[11 + r] = softplus_f(fdc[n * RANK + r]) * op;
    }
    __syncthreads();

    // ---- per-pixel accumulation in registers (vf4 LDS broadcast reads) ----
    float acc[RANK] = {0.f, 0.f, 0.f, 0.f, 0.f, 0.f};
    for (int i = 0; i < T; ++i) {
        const vf4* gv = (const vf4*)(glist + i * PSTRIDE);
        vf4 g0 = gv[0];
        vf4 g1 = gv[1];
        vf4 g2 = gv[2];
        float dx = px - g0.x;
        float dy = py - g0.y;
        float sigma = 0.5f * (g0.z * dx * dx + g1.x * dy * dy) + g0.w * dx * dy;
        if (sigma < 0.0f || sigma > SIGMA_CUT) continue;
        vf4 g3 = gv[3];
        vf4 g4 = gv[4];
        float wm = __expf(-sigma) *
                   (1.0f + g2.y * __cosf(g1.y * dx + g1.z * dy)
                         + g2.z * __cosf(g1.w * dx + g2.x * dy));
        acc[0] = fmaf(wm, g2.w, acc[0]);
        acc[1] = fmaf(wm, g3.x, acc[1]);
        acc[2] = fmaf(wm, g3.y, acc[2]);
        acc[3] = fmaf(wm, g3.z, acc[3]);
        acc[4] = fmaf(wm, g3.w, acc[4]);
        acc[5] = fmaf(wm, g4.x, acc[5]);
    }
#pragma unroll
    for (int r = 0; r < RANK; ++r) acc[r] = fmaxf(acc[r], 0.0f);

    // ---- transpose: accT[r][q], q = tile-linear pixel = t ----
#pragma unroll
    for (int r = 0; r < RANK; ++r)
        accT[r * TPAD + t] = acc[r];        // stride-1 lanes: conflict-free
    __syncthreads();

    // ---- output phase: thread t owns 4 px (q0=4*(t&63)) x 16 channels ----
    const int u    = t & 63;
    const int wv2  = t >> 6;
    const int row  = (u >> 4);              // 0..3 (tile y)
    const int xg   = (u & 15);              // 0..15 (x group of 4)
    const int p0   = (ty + row) * WW + tx + xg * 4;   // 4 consecutive px

    vf4 ab[RANK];
#pragma unroll
    for (int r = 0; r < RANK; ++r)
        ab[r] = *(const vf4*)(accT + r * TPAD + 4 * u);   // ds_read_b128

    // abundance output [p][r], 24 contiguous floats per thread (wave 0 only)
    if (cg == 0 && wv2 == 0) {
        vf4* ao = (vf4*)(abund + (size_t)p0 * RANK);
        vf4 o0 = { ab[0][0], ab[1][0], ab[2][0], ab[3][0] };
        vf4 o1 = { ab[4][0], ab[5][0], ab[0][1], ab[1][1] };
        vf4 o2 = { ab[2][1], ab[3][1], ab[4][1], ab[5][1] };
        vf4 o3 = { ab[0][2], ab[1][2], ab[2][2], ab[3][2] };
        vf4 o4 = { ab[4][2], ab[5][2], ab[0][3], ab[1][3] };
        vf4 o5 = { ab[2][3], ab[3][3], ab[4][3], ab[5][3] };
        __builtin_nontemporal_store(o0, ao + 0);
        __builtin_nontemporal_store(o1, ao + 1);
        __builtin_nontemporal_store(o2, ao + 2);
        __builtin_nontemporal_store(o3, ao + 3);
        __builtin_nontemporal_store(o4, ao + 4);
        __builtin_nontemporal_store(o5, ao + 5);
    }

    // render: 16 channels/thread, dwordx4 NT stores (wave: 4x256B segments)
    float* rp = render + (size_t)cg * 64 * PIX + p0;
#pragma unroll
    for (int i = 0; i < 16; ++i) {
        const int cl = wv2 * 16 + i;
        const vf4 e0 = *(const vf4*)(Els + cl * 8);       // broadcast
        const vf4 e1 = *(const vf4*)(Els + cl * 8 + 4);
        vf4 o = ab[0] * e0.x;
        o += ab[1] * e0.y;
        o += ab[2] * e0.z;
        o += ab[3] * e0.w;
        o += ab[4] * e1.x;
        o += ab[5] * e1.y;
        __builtin_nontemporal_store(o, (vf4*)(rp + (size_t)cl * PIX));
    }
}

extern "C" void kernel_launch(void* const* d_in, const int* in_sizes, int n_in,
                              void* d_out, int out_size, void* d_ws, size_t ws_size,
                              hipStream_t stream)
{
    const float* xyz             = (const float*)d_in[0];
    const float* cholesky        = (const float*)d_in[1];
    const float* features_dc     = (const float*)d_in[2];
    const float* gabor_freqs     = (const float*)d_in[3];
    const float* gabor_weights   = (const float*)d_in[4];
    const float* lora_U          = (const float*)d_in[5];
    const float* lora_V          = (const float*)d_in[6];
    const float* lora_scale_logit= (const float*)d_in[7];
    const float* opacity         = (const float*)d_in[8];
    const float* endmember       = (const float*)d_in[9];

    float* out    = (float*)d_out;
    float* render = out;                               // NC*PIX
    float* abund  = out + (size_t)NC * PIX;            // PIX*RANK
    float* Eout   = abund + (size_t)PIX * RANK;        // RANK*NC

    fused_kernel<<<512, 256, 0, stream>>>(
        xyz, cholesky, features_dc, gabor_freqs, gabor_weights, opacity,
        lora_U, lora_V, lora_scale_logit, endmember, render, abund, Eout);
}